// Round 6
// baseline (1163.516 us; speedup 1.0000x reference)
//
#include <hip/hip_runtime.h>
#include <hip/hip_fp16.h>

// GCN 3-layer forward. R6 = R5 (CSR pull, pre-scaled rows, padded int4 edge
// lists, fp16 intermediates) + fp16 A' + single-kernel per-bucket CSR build.
// Evidence: uniform random gathers pin at ~3.77 TB/s TCC-fetch regardless of
// structure/ILP (R3,R5) -> minimize lines+bytes per edge and build overhead.

typedef unsigned int uint;
typedef unsigned char uchar;

#define NB 256            // dst buckets (dst >> 11), 2048 nodes each
#define BKN 2048
#define PT_THREADS 256
#define PT_TILE 4096      // 16 edges per thread
#define SLAB_SLACK 6400   // per-bucket srcS slack for pad-to-4 (max 3*2048+3)

// ---- bucket histogram ----
__global__ void k_hist(const int* __restrict__ dst, int E, uint* __restrict__ bcnt) {
    __shared__ uint h[NB];
    int t = threadIdx.x;
    if (t < NB) h[t] = 0;
    __syncthreads();
    for (long long e = (long long)blockIdx.x * 256 + t; e < E; e += (long long)gridDim.x * 256)
        atomicAdd(&h[((uint)dst[e]) >> 11], 1u);
    __syncthreads();
    if (t < NB && h[t]) atomicAdd(&bcnt[t], h[t]);
}

// single block, NB threads: exclusive scan -> bbase[0..NB], init gcur
__global__ void k_scan_buckets(const uint* __restrict__ bcnt, uint* __restrict__ bbase,
                               uint* __restrict__ gcur) {
    __shared__ uint s[NB];
    int t = threadIdx.x;
    uint v = bcnt[t];
    s[t] = v;
    __syncthreads();
    for (int off = 1; off < NB; off <<= 1) {
        uint x = (t >= off) ? s[t - off] : 0u;
        __syncthreads();
        s[t] += x;
        __syncthreads();
    }
    uint ex = s[t] - v;
    bbase[t] = ex;
    gcur[t] = ex;
    if (t == NB - 1) bbase[NB] = s[t];
}

// ---- LDS-staged partition: edges -> bucketed (packed src | dstLocal<<19) ----
__global__ __launch_bounds__(PT_THREADS) void k_part(const int* __restrict__ src,
                                                     const int* __restrict__ dst, int E,
                                                     uint* __restrict__ gcur,
                                                     uint* __restrict__ bucketed) {
    __shared__ uint stage[PT_TILE];
    __shared__ uchar sbuck[PT_TILE];
    __shared__ uint hist[NB], lofs[NB], base[NB];
    int t = threadIdx.x;
    long long start = (long long)blockIdx.x * PT_TILE;
    int cnt = (int)min((long long)PT_TILE, (long long)E - start);

    hist[t] = 0;
    __syncthreads();
    uint myb[16], myr[16], mys[16];
#pragma unroll
    for (int k = 0; k < 16; ++k) {
        int idx = t + k * PT_THREADS;
        if (idx < cnt) {
            uint d = (uint)dst[start + idx];
            uint s = (uint)src[start + idx];
            uint b = d >> 11;
            myb[k] = b;
            mys[k] = s | ((d & 2047u) << 19);
            myr[k] = atomicAdd(&hist[b], 1u);
        }
    }
    __syncthreads();
    uint v = hist[t];
    lofs[t] = v;
    __syncthreads();
    for (int off = 1; off < NB; off <<= 1) {
        uint x = (t >= off) ? lofs[t - off] : 0u;
        __syncthreads();
        lofs[t] += x;
        __syncthreads();
    }
    uint ex = lofs[t] - v;
    __syncthreads();
    lofs[t] = ex;
    base[t] = atomicAdd(&gcur[t], v);
    __syncthreads();
#pragma unroll
    for (int k = 0; k < 16; ++k) {
        int idx = t + k * PT_THREADS;
        if (idx < cnt) {
            uint pos = lofs[myb[k]] + myr[k];
            stage[pos] = mys[k];
            sbuck[pos] = (uchar)myb[k];
        }
    }
    __syncthreads();
#pragma unroll
    for (int k = 0; k < 16; ++k) {
        int idx = t + k * PT_THREADS;
        if (idx < cnt) {
            uint b = sbuck[idx];
            bucketed[base[b] + ((uint)idx - lofs[b])] = stage[idx];
        }
    }
}

// ---- merged per-bucket CSR build: deg -> dis, padded scan -> rowp2, fill+pad ----
// One block per bucket. Bucket slab in srcS: align4(bbase[b]) + b*SLAB_SLACK.
// Second edge read is L2-hot (~250KB, just read in phase 1).
__global__ __launch_bounds__(256) void k_csr(const uint* __restrict__ bucketed,
                                             const uint* __restrict__ bbase,
                                             uint2* __restrict__ rowp2,
                                             float* __restrict__ dis,
                                             int* __restrict__ srcS, int N) {
    __shared__ uint c[BKN];
    __shared__ uint cur[BKN];
    __shared__ uint tsum[256];
    int b = blockIdx.x, t = threadIdx.x;
    uint beg = bbase[b], end = bbase[b + 1];
    for (int i = t; i < BKN; i += 256) c[i] = 0;
    __syncthreads();
    for (uint e = beg + t; e < end; e += 256) atomicAdd(&c[bucketed[e] >> 19], 1u);
    __syncthreads();
    // per-thread serial scan of 8 padded counts + 256-wide block scan
    uint loc[8];
    uint s = 0;
#pragma unroll
    for (int k = 0; k < 8; ++k) {
        uint pc = (c[t * 8 + k] + 3u) & ~3u;
        loc[k] = s;
        s += pc;
    }
    tsum[t] = s;
    __syncthreads();
    for (int off = 1; off < 256; off <<= 1) {
        uint x = (t >= off) ? tsum[t - off] : 0u;
        __syncthreads();
        tsum[t] += x;
        __syncthreads();
    }
    uint slab = ((beg + 3u) & ~3u) + (uint)b * SLAB_SLACK;
    uint tbase = slab + tsum[t] - s;
    int nodeBase = b * BKN;
#pragma unroll
    for (int k = 0; k < 8; ++k) {
        int i = t * 8 + k;
        int node = nodeBase + i;
        uint startp = tbase + loc[k];
        uint pc = (c[i] + 3u) & ~3u;
        cur[i] = startp;
        if (node < N) {
            rowp2[node] = make_uint2(startp, startp + pc);
            dis[node] = rsqrtf((float)(c[i] + 1u));   // +1 self-loop
        }
    }
    __syncthreads();
    for (uint e = beg + t; e < end; e += 256) {
        uint v = bucketed[e];
        uint pos = atomicAdd(&cur[v >> 19], 1u);
        srcS[pos] = (int)(v & 0x7ffffu);
    }
    __syncthreads();
#pragma unroll
    for (int k = 0; k < 8; ++k) {
        int i = t * 8 + k;
        if (nodeBase + i >= N) continue;
        uint ce = cur[i];
        uint pe = (ce + 3u) & ~3u;   // == startp + pc (startp 4-aligned)
        for (uint p = ce; p < pe; ++p) srcS[p] = N;   // sentinel zero-row
    }
}

// ---- layer-1: A'[i,0:15] = (x[i,:]@W1) * dis[i] -> fp16, A'[i,15]=0 ----
__global__ void k_lin_first(const float* __restrict__ x, const float* __restrict__ W,
                            const float* __restrict__ dis, __half* __restrict__ A, int N) {
    int i = blockIdx.x * blockDim.x + threadIdx.x;
    if (i >= N) return;
    float in[15];
#pragma unroll
    for (int j = 0; j < 15; ++j) in[j] = x[i * 15 + j];
    float di = dis[i];
#pragma unroll
    for (int o = 0; o < 15; ++o) {
        float acc = 0.f;
#pragma unroll
        for (int j = 0; j < 15; ++j) acc = fmaf(in[j], W[j * 15 + o], acc);
        A[i * 16 + o] = __float2half(acc * di);
    }
    A[i * 16 + 15] = __float2half(0.f);
}

// ---- pull 1: fp16 A' -> relu(dis*Sum + b1) @ W2 -> fp16 B' (pre-scaled) ----
__global__ void k_pull1(const __half* __restrict__ Ap, const int* __restrict__ srcS,
                        const uint2* __restrict__ rowp2, const float* __restrict__ dis,
                        const float* __restrict__ W2, const float* __restrict__ b1,
                        __half* __restrict__ Bp, int N) {
    __shared__ float v[16 * 16];
    int tid = blockIdx.x * blockDim.x + threadIdx.x;
    int node = tid >> 4;
    int j = tid & 15;
    int local = threadIdx.x >> 4;
    bool valid = node < N;
    float di = 0.f;
    if (valid) {
        di = dis[node];
        float acc = __half2float(Ap[node * 16 + j]);   // self term (pre-scaled)
        uint2 rp = rowp2[node];
        for (uint e = rp.x; e < rp.y; e += 4) {
            int4 s4 = *(const int4*)(srcS + e);        // 16B-aligned
            float h0 = __half2float(Ap[s4.x * 16 + j]);
            float h1 = __half2float(Ap[s4.y * 16 + j]);
            float h2 = __half2float(Ap[s4.z * 16 + j]);
            float h3 = __half2float(Ap[s4.w * 16 + j]);
            acc += (h0 + h1) + (h2 + h3);
        }
        float val = (j < 15) ? (acc * di + b1[j]) : 0.f;
        v[local * 16 + j] = val > 0.f ? val : 0.f;
    } else {
        v[local * 16 + j] = 0.f;
    }
    __syncthreads();
    if (valid) {
        float o = 0.f;
        if (j < 15) {
#pragma unroll
            for (int k = 0; k < 15; ++k) o = fmaf(v[local * 16 + k], W2[k * 15 + j], o);
        }
        Bp[node * 16 + j] = __float2half((j < 15 ? o : 0.f) * di);
    }
}

// ---- pull 2: fp16 B' -> relu(dis*Sum + b2) @ W3 -> fp16 C' (pre-scaled, 4-wide) ----
__global__ void k_pull2(const __half* __restrict__ Bp, const int* __restrict__ srcS,
                        const uint2* __restrict__ rowp2, const float* __restrict__ dis,
                        const float* __restrict__ W3, const float* __restrict__ b2,
                        __half* __restrict__ Cp, int N) {
    __shared__ float v[16 * 16];
    int tid = blockIdx.x * blockDim.x + threadIdx.x;
    int node = tid >> 4;
    int j = tid & 15;
    int local = threadIdx.x >> 4;
    bool valid = node < N;
    float di = 0.f;
    if (valid) {
        di = dis[node];
        float acc = __half2float(Bp[node * 16 + j]);
        uint2 rp = rowp2[node];
        for (uint e = rp.x; e < rp.y; e += 4) {
            int4 s4 = *(const int4*)(srcS + e);
            float h0 = __half2float(Bp[s4.x * 16 + j]);
            float h1 = __half2float(Bp[s4.y * 16 + j]);
            float h2 = __half2float(Bp[s4.z * 16 + j]);
            float h3 = __half2float(Bp[s4.w * 16 + j]);
            acc += (h0 + h1) + (h2 + h3);
        }
        float val = (j < 15) ? (acc * di + b2[j]) : 0.f;
        v[local * 16 + j] = val > 0.f ? val : 0.f;
    } else {
        v[local * 16 + j] = 0.f;
    }
    __syncthreads();
    if (valid && j < 4) {
        float o = 0.f;
#pragma unroll
        for (int k = 0; k < 15; ++k) o = fmaf(v[local * 16 + k], W3[k * 4 + j], o);
        Cp[node * 4 + j] = __float2half(o * di);
    }
}

// ---- pull 3: fp16 C' (4MB, mostly L2-resident) -> out fp32 ----
__global__ void k_pull3(const __half* __restrict__ Cp, const int* __restrict__ srcS,
                        const uint2* __restrict__ rowp2, const float* __restrict__ dis,
                        const float* __restrict__ b3, float* __restrict__ out, int N) {
    int tid = blockIdx.x * blockDim.x + threadIdx.x;
    int node = tid >> 2;
    int j = tid & 3;
    if (node >= N) return;
    float acc = __half2float(Cp[node * 4 + j]);
    uint2 rp = rowp2[node];
    for (uint e = rp.x; e < rp.y; e += 4) {
        int4 s4 = *(const int4*)(srcS + e);
        float h0 = __half2float(Cp[s4.x * 4 + j]);
        float h1 = __half2float(Cp[s4.y * 4 + j]);
        float h2 = __half2float(Cp[s4.z * 4 + j]);
        float h3 = __half2float(Cp[s4.w * 4 + j]);
        acc += (h0 + h1) + (h2 + h3);
    }
    out[(size_t)node * 4 + j] = acc * dis[node] + b3[j];
}

extern "C" void kernel_launch(void* const* d_in, const int* in_sizes, int n_in,
                              void* d_out, int out_size, void* d_ws, size_t ws_size,
                              hipStream_t stream) {
    const float* x  = (const float*)d_in[0];
    const int*   ei = (const int*)d_in[1];
    const float* W1 = (const float*)d_in[3];
    const float* b1 = (const float*)d_in[4];
    const float* W2 = (const float*)d_in[5];
    const float* b2 = (const float*)d_in[6];
    const float* W3 = (const float*)d_in[7];
    const float* b3 = (const float*)d_in[8];
    float* out = (float*)d_out;

    const int N = in_sizes[0] / 15;
    const int E = in_sizes[1] / 2;
    const int* src = ei;
    const int* dst = ei + E;
    const int NBr = (N + BKN - 1) / BKN;   // live buckets (245)

    char* ws = (char*)d_ws;
    auto align = [](size_t v) { return (v + 255) & ~(size_t)255; };
    size_t off = 0;
    uint2* rowp2 = (uint2*)(ws + off); off += align((size_t)N * 8);
    float* dis   = (float*)(ws + off); off += align((size_t)N * 4);
    uint* bcnt   = (uint*)(ws + off); off += align((size_t)NB * 4);
    uint* bbase  = (uint*)(ws + off); off += align((size_t)(NB + 1) * 4);
    uint* gcur   = (uint*)(ws + off); off += align((size_t)NB * 4);
    int*  srcS   = (int*)(ws + off);  off += align(((size_t)E + (size_t)NB * SLAB_SLACK + 1024) * 4);
    // slabY: bucketed (64MB) dead after k_csr, overlaid by B'(fp16)+C'(fp16)
    char* slabY = ws + off;
    uint*   bucketed = (uint*)slabY;
    __half* Bp = (__half*)slabY;
    __half* Cp = (__half*)(slabY + align((size_t)(N + 1) * 16 * 2));
    off += align(max((size_t)E * 4,
                     align((size_t)(N + 1) * 16 * 2) + (size_t)(N + 1) * 4 * 2));
    __half* Ap = (__half*)(ws + off);  // (N+1) x 16 fp16

    const int nTiles = (E + PT_TILE - 1) / PT_TILE;
    const int gN16 = (int)(((long long)N * 16 + 255) / 256);
    const int gN4  = (int)(((long long)N * 4 + 255) / 256);
    const int nbN  = (N + 255) / 256;

    // CSR build
    hipMemsetAsync(bcnt, 0, (size_t)NB * 4, stream);
    k_hist<<<2048, 256, 0, stream>>>(dst, E, bcnt);
    k_scan_buckets<<<1, NB, 0, stream>>>(bcnt, bbase, gcur);
    k_part<<<nTiles, PT_THREADS, 0, stream>>>(src, dst, E, gcur, bucketed);
    k_csr<<<NBr, 256, 0, stream>>>(bucketed, bbase, rowp2, dis, srcS, N);
    // bucketed dead -> slabY becomes B'/C'

    k_lin_first<<<nbN, 256, 0, stream>>>(x, W1, dis, Ap, N);
    // sentinel zero-rows (row N) — ws re-poisoned every call
    hipMemsetAsync(Ap + (size_t)N * 16, 0, 16 * 2, stream);
    hipMemsetAsync(Bp + (size_t)N * 16, 0, 16 * 2, stream);
    hipMemsetAsync(Cp + (size_t)N * 4, 0, 4 * 2, stream);

    k_pull1<<<gN16, 256, 0, stream>>>(Ap, srcS, rowp2, dis, W2, b1, Bp, N);
    k_pull2<<<gN16, 256, 0, stream>>>(Bp, srcS, rowp2, dis, W3, b2, Cp, N);
    k_pull3<<<gN4, 256, 0, stream>>>(Cp, srcS, rowp2, dis, b3, out, N);
}

// Round 7
// 999.708 us; speedup vs baseline: 1.1639x; 1.1639x over previous
//
#include <hip/hip_runtime.h>
#include <hip/hip_fp16.h>

// GCN 3-layer forward. R7 = R6 pulls (line-count-bound floor) + rebuilt CSR:
//  - k_csr: full LDS counting sort per 1024-node bucket -> sequential
//    dwordx4 writes (R6's cursor scatter caused 431MB write amplification)
//  - k_part: NB=512 / 512 thr / tile 8192 (64B runs, 54KB LDS, 2 blk/CU)
// Pull kernels at the measured ~62G lines/s random-gather ceiling.

typedef unsigned int uint;
typedef unsigned short ushort;

#define NB 512            // dst buckets (dst >> 10), 1024 nodes each
#define BKN 1024
#define PT_THREADS 512
#define PT_TILE 8192      // 16 edges per thread
#define SLAB_SLACK 4096   // per-bucket srcS slack for pad-to-4 (max 3*1024+3)
#define STAGE_CAP 36864   // LDS stage entries (mean 32768, sd ~128 -> +32 sigma)

// ---- bucket histogram ----
__global__ void k_hist(const int* __restrict__ dst, int E, uint* __restrict__ bcnt) {
    __shared__ uint h[NB];
    int t = threadIdx.x;
    for (int i = t; i < NB; i += 256) h[i] = 0;
    __syncthreads();
    for (long long e = (long long)blockIdx.x * 256 + t; e < E; e += (long long)gridDim.x * 256)
        atomicAdd(&h[((uint)dst[e]) >> 10], 1u);
    __syncthreads();
    for (int i = t; i < NB; i += 256) if (h[i]) atomicAdd(&bcnt[i], h[i]);
}

// single block, NB threads: exclusive scan -> bbase[0..NB], init gcur
__global__ void k_scan_buckets(const uint* __restrict__ bcnt, uint* __restrict__ bbase,
                               uint* __restrict__ gcur) {
    __shared__ uint s[NB];
    int t = threadIdx.x;
    uint v = bcnt[t];
    s[t] = v;
    __syncthreads();
    for (int off = 1; off < NB; off <<= 1) {
        uint x = (t >= off) ? s[t - off] : 0u;
        __syncthreads();
        s[t] += x;
        __syncthreads();
    }
    uint ex = s[t] - v;
    bbase[t] = ex;
    gcur[t] = ex;
    if (t == NB - 1) bbase[NB] = s[t];
}

// ---- LDS-staged partition: edges -> bucketed (packed src | dstLocal<<19) ----
__global__ __launch_bounds__(PT_THREADS) void k_part(const int* __restrict__ src,
                                                     const int* __restrict__ dst, int E,
                                                     uint* __restrict__ gcur,
                                                     uint* __restrict__ bucketed) {
    __shared__ uint stage[PT_TILE];
    __shared__ ushort sbuck[PT_TILE];
    __shared__ uint hist[NB], lofs[NB], base[NB];
    int t = threadIdx.x;
    long long start = (long long)blockIdx.x * PT_TILE;
    int cnt = (int)min((long long)PT_TILE, (long long)E - start);

    hist[t] = 0;
    __syncthreads();
    uint myb[16], myr[16], mys[16];
#pragma unroll
    for (int k = 0; k < 16; ++k) {
        int idx = t + k * PT_THREADS;
        if (idx < cnt) {
            uint d = (uint)dst[start + idx];
            uint s = (uint)src[start + idx];
            uint b = d >> 10;
            myb[k] = b;
            mys[k] = s | ((d & 1023u) << 19);
            myr[k] = atomicAdd(&hist[b], 1u);
        }
    }
    __syncthreads();
    uint v = hist[t];
    lofs[t] = v;
    __syncthreads();
    for (int off = 1; off < NB; off <<= 1) {
        uint x = (t >= off) ? lofs[t - off] : 0u;
        __syncthreads();
        lofs[t] += x;
        __syncthreads();
    }
    uint ex = lofs[t] - v;
    __syncthreads();
    lofs[t] = ex;
    base[t] = atomicAdd(&gcur[t], v);
    __syncthreads();
#pragma unroll
    for (int k = 0; k < 16; ++k) {
        int idx = t + k * PT_THREADS;
        if (idx < cnt) {
            uint pos = lofs[myb[k]] + myr[k];
            stage[pos] = mys[k];
            sbuck[pos] = (ushort)myb[k];
        }
    }
    __syncthreads();
#pragma unroll
    for (int k = 0; k < 16; ++k) {
        int idx = t + k * PT_THREADS;
        if (idx < cnt) {
            uint b = sbuck[idx];
            bucketed[base[b] + ((uint)idx - lofs[b])] = stage[idx];
        }
    }
}

// ---- per-bucket CSR build via full LDS counting sort; sequential writes ----
__global__ __launch_bounds__(512) void k_csr(const uint* __restrict__ bucketed,
                                             const uint* __restrict__ bbase,
                                             uint2* __restrict__ rowp2,
                                             float* __restrict__ dis,
                                             int* __restrict__ srcS, int N) {
    __shared__ uint c[BKN];
    __shared__ uint cur[BKN];
    __shared__ uint tsum[512];
    __shared__ __align__(16) int stage[STAGE_CAP];
    int b = blockIdx.x, t = threadIdx.x;
    uint beg = bbase[b], end = bbase[b + 1];
    for (int i = t; i < BKN; i += 512) c[i] = 0;
    __syncthreads();
    for (uint e = beg + t; e < end; e += 512) atomicAdd(&c[bucketed[e] >> 19], 1u);
    __syncthreads();
    // padded scan: 2 counters per thread + 512-wide block scan
    uint c0 = c[2 * t], c1 = c[2 * t + 1];
    uint pc0 = (c0 + 3u) & ~3u;
    uint pc1 = (c1 + 3u) & ~3u;
    tsum[t] = pc0 + pc1;
    __syncthreads();
    for (int off = 1; off < 512; off <<= 1) {
        uint x = (t >= off) ? tsum[t - off] : 0u;
        __syncthreads();
        tsum[t] += x;
        __syncthreads();
    }
    uint tot = tsum[511];                       // total padded entries
    uint base0 = tsum[t] - (pc0 + pc1);         // exclusive base for node 2t
    uint slab = ((beg + 3u) & ~3u) + (uint)b * SLAB_SLACK;
    int nodeBase = b * BKN;
    cur[2 * t] = base0;
    cur[2 * t + 1] = base0 + pc0;
    int n0 = nodeBase + 2 * t, n1 = n0 + 1;
    if (n0 < N) {
        rowp2[n0] = make_uint2(slab + base0, slab + base0 + pc0);
        dis[n0] = rsqrtf((float)(c0 + 1u));     // +1 self-loop
    }
    if (n1 < N) {
        rowp2[n1] = make_uint2(slab + base0 + pc0, slab + base0 + pc0 + pc1);
        dis[n1] = rsqrtf((float)(c1 + 1u));
    }
    __syncthreads();
    // init staged range to sentinel (pad slots keep N)
    uint capped = min(tot, (uint)STAGE_CAP);
    for (uint i = t; i < capped; i += 512) stage[i] = N;
    for (uint i = (uint)STAGE_CAP + t; i < tot; i += 512) srcS[slab + i] = N;  // ~never
    __syncthreads();
    // fill in final order (LDS cursors, LDS stage)
    for (uint e = beg + t; e < end; e += 512) {
        uint v = bucketed[e];
        uint idx = atomicAdd(&cur[v >> 19], 1u);
        int sv = (int)(v & 0x7ffffu);
        if (idx < (uint)STAGE_CAP) stage[idx] = sv;
        else srcS[slab + idx] = sv;             // ~never
    }
    __syncthreads();
    // sequential dwordx4 writeout
    for (uint i = t * 4; i < capped; i += 512 * 4)
        *(int4*)(srcS + slab + i) = *(const int4*)(stage + i);
}

// ---- layer-1: A'[i,0:15] = (x[i,:]@W1) * dis[i] -> fp16, A'[i,15]=0 ----
__global__ void k_lin_first(const float* __restrict__ x, const float* __restrict__ W,
                            const float* __restrict__ dis, __half* __restrict__ A, int N) {
    int i = blockIdx.x * blockDim.x + threadIdx.x;
    if (i >= N) return;
    float in[15];
#pragma unroll
    for (int j = 0; j < 15; ++j) in[j] = x[i * 15 + j];
    float di = dis[i];
#pragma unroll
    for (int o = 0; o < 15; ++o) {
        float acc = 0.f;
#pragma unroll
        for (int j = 0; j < 15; ++j) acc = fmaf(in[j], W[j * 15 + o], acc);
        A[i * 16 + o] = __float2half(acc * di);
    }
    A[i * 16 + 15] = __float2half(0.f);
}

// ---- pull 1: fp16 A' -> relu(dis*Sum + b1) @ W2 -> fp16 B' (pre-scaled) ----
__global__ void k_pull1(const __half* __restrict__ Ap, const int* __restrict__ srcS,
                        const uint2* __restrict__ rowp2, const float* __restrict__ dis,
                        const float* __restrict__ W2, const float* __restrict__ b1,
                        __half* __restrict__ Bp, int N) {
    __shared__ float v[16 * 16];
    int tid = blockIdx.x * blockDim.x + threadIdx.x;
    int node = tid >> 4;
    int j = tid & 15;
    int local = threadIdx.x >> 4;
    bool valid = node < N;
    float di = 0.f;
    if (valid) {
        di = dis[node];
        float acc = __half2float(Ap[node * 16 + j]);   // self term (pre-scaled)
        uint2 rp = rowp2[node];
        for (uint e = rp.x; e < rp.y; e += 4) {
            int4 s4 = *(const int4*)(srcS + e);        // 16B-aligned
            float h0 = __half2float(Ap[s4.x * 16 + j]);
            float h1 = __half2float(Ap[s4.y * 16 + j]);
            float h2 = __half2float(Ap[s4.z * 16 + j]);
            float h3 = __half2float(Ap[s4.w * 16 + j]);
            acc += (h0 + h1) + (h2 + h3);
        }
        float val = (j < 15) ? (acc * di + b1[j]) : 0.f;
        v[local * 16 + j] = val > 0.f ? val : 0.f;
    } else {
        v[local * 16 + j] = 0.f;
    }
    __syncthreads();
    if (valid) {
        float o = 0.f;
        if (j < 15) {
#pragma unroll
            for (int k = 0; k < 15; ++k) o = fmaf(v[local * 16 + k], W2[k * 15 + j], o);
        }
        Bp[node * 16 + j] = __float2half((j < 15 ? o : 0.f) * di);
    }
}

// ---- pull 2: fp16 B' -> relu(dis*Sum + b2) @ W3 -> fp16 C' (pre-scaled, 4-wide) ----
__global__ void k_pull2(const __half* __restrict__ Bp, const int* __restrict__ srcS,
                        const uint2* __restrict__ rowp2, const float* __restrict__ dis,
                        const float* __restrict__ W3, const float* __restrict__ b2,
                        __half* __restrict__ Cp, int N) {
    __shared__ float v[16 * 16];
    int tid = blockIdx.x * blockDim.x + threadIdx.x;
    int node = tid >> 4;
    int j = tid & 15;
    int local = threadIdx.x >> 4;
    bool valid = node < N;
    float di = 0.f;
    if (valid) {
        di = dis[node];
        float acc = __half2float(Bp[node * 16 + j]);
        uint2 rp = rowp2[node];
        for (uint e = rp.x; e < rp.y; e += 4) {
            int4 s4 = *(const int4*)(srcS + e);
            float h0 = __half2float(Bp[s4.x * 16 + j]);
            float h1 = __half2float(Bp[s4.y * 16 + j]);
            float h2 = __half2float(Bp[s4.z * 16 + j]);
            float h3 = __half2float(Bp[s4.w * 16 + j]);
            acc += (h0 + h1) + (h2 + h3);
        }
        float val = (j < 15) ? (acc * di + b2[j]) : 0.f;
        v[local * 16 + j] = val > 0.f ? val : 0.f;
    } else {
        v[local * 16 + j] = 0.f;
    }
    __syncthreads();
    if (valid && j < 4) {
        float o = 0.f;
#pragma unroll
        for (int k = 0; k < 15; ++k) o = fmaf(v[local * 16 + k], W3[k * 4 + j], o);
        Cp[node * 4 + j] = __float2half(o * di);
    }
}

// ---- pull 3: fp16 C' (4MB, mostly L2-resident) -> out fp32 ----
__global__ void k_pull3(const __half* __restrict__ Cp, const int* __restrict__ srcS,
                        const uint2* __restrict__ rowp2, const float* __restrict__ dis,
                        const float* __restrict__ b3, float* __restrict__ out, int N) {
    int tid = blockIdx.x * blockDim.x + threadIdx.x;
    int node = tid >> 2;
    int j = tid & 3;
    if (node >= N) return;
    float acc = __half2float(Cp[node * 4 + j]);
    uint2 rp = rowp2[node];
    for (uint e = rp.x; e < rp.y; e += 4) {
        int4 s4 = *(const int4*)(srcS + e);
        float h0 = __half2float(Cp[s4.x * 4 + j]);
        float h1 = __half2float(Cp[s4.y * 4 + j]);
        float h2 = __half2float(Cp[s4.z * 4 + j]);
        float h3 = __half2float(Cp[s4.w * 4 + j]);
        acc += (h0 + h1) + (h2 + h3);
    }
    out[(size_t)node * 4 + j] = acc * dis[node] + b3[j];
}

extern "C" void kernel_launch(void* const* d_in, const int* in_sizes, int n_in,
                              void* d_out, int out_size, void* d_ws, size_t ws_size,
                              hipStream_t stream) {
    const float* x  = (const float*)d_in[0];
    const int*   ei = (const int*)d_in[1];
    const float* W1 = (const float*)d_in[3];
    const float* b1 = (const float*)d_in[4];
    const float* W2 = (const float*)d_in[5];
    const float* b2 = (const float*)d_in[6];
    const float* W3 = (const float*)d_in[7];
    const float* b3 = (const float*)d_in[8];
    float* out = (float*)d_out;

    const int N = in_sizes[0] / 15;
    const int E = in_sizes[1] / 2;
    const int* src = ei;
    const int* dst = ei + E;
    const int NBr = (N + BKN - 1) / BKN;   // live buckets (489)

    char* ws = (char*)d_ws;
    auto align = [](size_t v) { return (v + 255) & ~(size_t)255; };
    size_t off = 0;
    uint2* rowp2 = (uint2*)(ws + off); off += align((size_t)N * 8);
    float* dis   = (float*)(ws + off); off += align((size_t)N * 4);
    uint* bcnt   = (uint*)(ws + off); off += align((size_t)NB * 4);
    uint* bbase  = (uint*)(ws + off); off += align((size_t)(NB + 1) * 4);
    uint* gcur   = (uint*)(ws + off); off += align((size_t)NB * 4);
    int*  srcS   = (int*)(ws + off);  off += align(((size_t)E + (size_t)NB * SLAB_SLACK + 1024) * 4);
    // slabY: bucketed (64MB) dead after k_csr, overlaid by B'(fp16)+C'(fp16)
    char* slabY = ws + off;
    uint*   bucketed = (uint*)slabY;
    __half* Bp = (__half*)slabY;
    __half* Cp = (__half*)(slabY + align((size_t)(N + 1) * 16 * 2));
    off += align(max((size_t)E * 4,
                     align((size_t)(N + 1) * 16 * 2) + (size_t)(N + 1) * 4 * 2));
    __half* Ap = (__half*)(ws + off);  // (N+1) x 16 fp16

    const int nTiles = (E + PT_TILE - 1) / PT_TILE;
    const int gN16 = (int)(((long long)N * 16 + 255) / 256);
    const int gN4  = (int)(((long long)N * 4 + 255) / 256);
    const int nbN  = (N + 255) / 256;

    // CSR build
    hipMemsetAsync(bcnt, 0, (size_t)NB * 4, stream);
    k_hist<<<2048, 256, 0, stream>>>(dst, E, bcnt);
    k_scan_buckets<<<1, NB, 0, stream>>>(bcnt, bbase, gcur);
    k_part<<<nTiles, PT_THREADS, 0, stream>>>(src, dst, E, gcur, bucketed);
    k_csr<<<NBr, 512, 0, stream>>>(bucketed, bbase, rowp2, dis, srcS, N);
    // bucketed dead -> slabY becomes B'/C'

    k_lin_first<<<nbN, 256, 0, stream>>>(x, W1, dis, Ap, N);
    // sentinel zero-rows (row N) — ws re-poisoned every call
    hipMemsetAsync(Ap + (size_t)N * 16, 0, 16 * 2, stream);
    hipMemsetAsync(Bp + (size_t)N * 16, 0, 16 * 2, stream);
    hipMemsetAsync(Cp + (size_t)N * 4, 0, 4 * 2, stream);

    k_pull1<<<gN16, 256, 0, stream>>>(Ap, srcS, rowp2, dis, W2, b1, Bp, N);
    k_pull2<<<gN16, 256, 0, stream>>>(Bp, srcS, rowp2, dis, W3, b2, Cp, N);
    k_pull3<<<gN4, 256, 0, stream>>>(Cp, srcS, rowp2, dis, b3, out, N);
}